// Round 6
// baseline (171.325 us; speedup 1.0000x reference)
//
#include <hip/hip_runtime.h>

// Problem constants: B=2, T=2048, C=1024, H=16, HS=64
typedef unsigned short u16;
typedef unsigned int u32;
typedef __bf16 bf16x8 __attribute__((ext_vector_type(8)));
typedef float f32x4 __attribute__((ext_vector_type(4)));
typedef float f32x16 __attribute__((ext_vector_type(16)));
typedef u32 u32x4 __attribute__((ext_vector_type(4)));
typedef u16 u16x4 __attribute__((ext_vector_type(4)));
typedef u16 u16x8 __attribute__((ext_vector_type(8)));

__device__ __forceinline__ u16 f2bf(float f) {
  u32 u = __builtin_bit_cast(u32, f);
  u += 0x7fffu + ((u >> 16) & 1u);   // round-to-nearest-even
  return (u16)(u >> 16);
}

// pack two f32 -> two bf16 (round-half-up) in one u32; a in low half.
__device__ __forceinline__ u32 pk2(float a, float b) {
  u32 ua = __builtin_bit_cast(u32, a) + 0x8000u;
  u32 ub = __builtin_bit_cast(u32, b) + 0x8000u;
  return __builtin_amdgcn_perm(ub, ua, 0x07060302);  // {ub.hi16, ua.hi16}
}

__device__ __forceinline__ void gld16(const void* g, void* l) {
  __builtin_amdgcn_global_load_lds(
      (const __attribute__((address_space(1))) void*)g,
      (__attribute__((address_space(3))) void*)l, 16, 0, 0);
}

// ---------------- merged prep kernel (one launch) ----------------
__global__ __launch_bounds__(256) void k_prep(
    const float* __restrict__ x, u16* __restrict__ xb,
    const float* __restrict__ Wqkv, u16* __restrict__ Wqkvt,
    const float* __restrict__ Wproj, u16* __restrict__ Wpt,
    float2* __restrict__ rope) {
  __shared__ float tile[32][33];
  const int tid = threadIdx.x;
  int bx = blockIdx.x;
  if (bx < 4096) {
    int i = (bx * 256 + tid) * 4;
    float4 v = *(const float4*)(x + i);
    u16x4 o = { f2bf(v.x), f2bf(v.y), f2bf(v.z), f2bf(v.w) };
    *(u16x4*)(xb + i) = o;
    return;
  }
  bx -= 4096;
  const float* src; u16* dst; int R, Cc, bxx, byy;
  if (bx < 3072) {
    src = Wqkv; dst = Wqkvt; R = 1024; Cc = 3072; bxx = bx % 96; byy = bx / 96;
  } else if (bx < 4096) {
    int b = bx - 3072;
    src = Wproj; dst = Wpt; R = 1024; Cc = 1024; bxx = b % 32; byy = b / 32;
  } else {
    int i = (bx - 4096) * 256 + tid;  // 0..65535
    int t = i >> 5, d = i & 31;
    float theta = expf(-(float)d * 0.28782313662425575f);  // ln(10000)/32
    float ang = (float)t * theta;
    rope[i] = make_float2(cosf(ang), sinf(ang));
    return;
  }
  int xx = tid & 31, yy = tid >> 5;
  int c0 = bxx * 32, r0 = byy * 32;
  for (int i = 0; i < 4; ++i)
    tile[yy + 8 * i][xx] = src[(size_t)(r0 + yy + 8 * i) * Cc + c0 + xx];
  __syncthreads();
  for (int i = 0; i < 4; ++i)
    dst[(size_t)(c0 + yy + 8 * i) * R + r0 + xx] = f2bf(tile[xx][yy + 8 * i]);
}

// --------------- QKV GEMM + bias + RoPE + scatter ---------------
// Q is pre-scaled by 1/sqrt(HS)*log2(e) here so k_attn's softmax is a bare
// exp2 of the MFMA output.
__global__ __launch_bounds__(256, 4) void k_qkv(
    const u16* __restrict__ Xb,      // [4096][1024] bf16
    const u16* __restrict__ Wt,      // [3072][1024] bf16 (W_qkv^T)
    const float* __restrict__ bias,  // [3072]
    const float2* __restrict__ rope, // [2048][32]
    u16* __restrict__ Qg,            // [B,H,T,HS]  (scaled)
    u16* __restrict__ Kg,            // [B,H,T,HS]
    u16* __restrict__ Vt) {          // [B,H,HS,T]
  __shared__ alignas(16) u16 smem[18432];  // 36 KB: As|Bs in K-loop, Es after
  u16* As = smem;           // [128][64]
  u16* Bs = smem + 8192;    // [128][64]
  const int tid = threadIdx.x;
  const int lane = tid & 63, w = tid >> 6;
  const int quad = lane >> 4, l15 = lane & 15;
  const int m0 = blockIdx.y * 128, n0 = blockIdx.x * 128;
  const int wm = (w & 1) * 64, wn = (w >> 1) * 64;
  const int srow = lane >> 3, sj = lane & 7;
  const int sw = (sj ^ srow) * 8;   // swizzled source u16 offset
  const f32x4 vzero = {0.f, 0.f, 0.f, 0.f};

  f32x4 acc[4][4];  // [nt][mt] (swapped order)
  for (int i = 0; i < 4; ++i)
    for (int j = 0; j < 4; ++j) acc[i][j] = vzero;

  for (int kt = 0; kt < 1024; kt += 64) {
    __syncthreads();
    for (int i = 0; i < 4; ++i) {
      int row = w * 32 + i * 8;
      gld16(Xb + (size_t)(m0 + row + srow) * 1024 + kt + sw, &As[row * 64]);
      gld16(Wt + (size_t)(n0 + row + srow) * 1024 + kt + sw, &Bs[row * 64]);
    }
    __syncthreads();
    for (int ks = 0; ks < 2; ++ks) {
      const int cc = ((ks * 4 + quad) ^ (l15 & 7)) * 8;
      bf16x8 a[4], b[4];
      for (int mt = 0; mt < 4; ++mt)
        a[mt] = *(const bf16x8*)&As[(wm + mt * 16 + l15) * 64 + cc];
      for (int nt = 0; nt < 4; ++nt)
        b[nt] = *(const bf16x8*)&Bs[(wn + nt * 16 + l15) * 64 + cc];
      for (int nt = 0; nt < 4; ++nt)
        for (int mt = 0; mt < 4; ++mt)
          acc[nt][mt] = __builtin_amdgcn_mfma_f32_16x16x32_bf16(
              b[nt], a[mt], acc[nt][mt], 0, 0, 0);
    }
  }
  __syncthreads();  // all waves done reading As/Bs; safe to overwrite with Es

  // ---- stage into LDS (bias + RoPE applied), wave-uniform region per half
  const int half = w >> 1;
  const int nh = n0 + half * 64;             // 64-aligned -> single region
  const int region = (nh % 192) >> 6;        // 0=Q 1=K 2=V
  u16* Eh = smem + half * 9216;
  if (region < 2) {
    const float qsc = (region == 0) ? 0.18033688011112042f : 1.0f; // SCL into Q
    for (int nt = 0; nt < 4; ++nt) {
      float4 bv4 = *(const float4*)&bias[nh + nt * 16 + quad * 4];
      for (int mt = 0; mt < 4; ++mt) {
        int m_l = wm + mt * 16 + l15;
        int t = (m0 + m_l) & 2047;
        float4 cs = *(const float4*)&rope[t * 32 + nt * 8 + quad * 2];
        float v0 = acc[nt][mt][0] + bv4.x;
        float v1 = acc[nt][mt][1] + bv4.y;
        float v2 = acc[nt][mt][2] + bv4.z;
        float v3 = acc[nt][mt][3] + bv4.w;
        float r0 = fmaf(-v1, cs.y, v0 * cs.x) * qsc;
        float r1 = fmaf( v0, cs.y, v1 * cs.x) * qsc;
        float r2 = fmaf(-v3, cs.w, v2 * cs.z) * qsc;
        float r3 = fmaf( v2, cs.w, v3 * cs.z) * qsc;
        uint2 pv; pv.x = pk2(r0, r1); pv.y = pk2(r2, r3);
        *(uint2*)&Eh[m_l * 72 + nt * 16 + quad * 4] = pv;
      }
    }
  } else {
    // V: transposed [c][m] stride 136; c = nt*16+quad*4+r varies with r
    for (int nt = 0; nt < 4; ++nt) {
      float4 bv4 = *(const float4*)&bias[nh + nt * 16 + quad * 4];
      for (int mt = 0; mt < 4; ++mt) {
        int m_l = wm + mt * 16 + l15;
        int cb = nt * 16 + quad * 4;
        Eh[(cb + 0) * 136 + m_l] = f2bf(acc[nt][mt][0] + bv4.x);
        Eh[(cb + 1) * 136 + m_l] = f2bf(acc[nt][mt][1] + bv4.y);
        Eh[(cb + 2) * 136 + m_l] = f2bf(acc[nt][mt][2] + bv4.z);
        Eh[(cb + 3) * 136 + m_l] = f2bf(acc[nt][mt][3] + bv4.w);
      }
    }
  }
  __syncthreads();

  // ---- coalesced write-out: 16 B per lane
  const int bb = m0 >> 11, t0 = m0 & 2047;
  for (int hf = 0; hf < 2; ++hf) {
    const int nhf = n0 + hf * 64;
    const int hh = nhf / 192;
    const int reg = (nhf % 192) >> 6;
    const u16* Ef = smem + hf * 9216;
    if (reg < 2) {
      u16* dst = (reg == 0 ? Qg : Kg) +
                 ((size_t)(bb * 16 + hh) * 2048 + t0) * 64;
      int chunk = tid & 7, row0 = tid >> 3;
      for (int p = 0; p < 4; ++p) {
        int row = row0 + p * 32;
        u16x8 val = *(const u16x8*)&Ef[row * 72 + chunk * 8];
        *(u16x8*)(dst + (size_t)row * 64 + chunk * 8) = val;
      }
    } else {
      u16* dstv = Vt + (size_t)(bb * 16 + hh) * 64 * 2048 + t0;
      int mch = tid & 15, c0r = tid >> 4;
      for (int p = 0; p < 4; ++p) {
        int c = c0r + p * 16;
        u16x8 val = *(const u16x8*)&Ef[c * 136 + mch * 8];
        *(u16x8*)(dstv + (size_t)c * 2048 + mch * 8) = val;
      }
    }
  }
}

// ------------------- flash attention (causal) -------------------
// 32x32 IN-REGISTER-SOFTMAX ROUND (m214-v22 structure, 4-wave form):
// - 256 blocks, 4 waves; wave owns 32 q-rows, block 128; sequential uniform
//   pair {t, 15-t} = 34 KV-iters for every block; XCD-affine decode.
// - mfma_f32_32x32x16_bf16, swapped QK^T (S^T = K.Q^T): lane&31 = q, the 16
//   regs (+lane>>5) = k -> softmax row is lane-local; lsum needs only one
//   shfl_xor(32) at epilogue.
// - P NEVER goes through LDS: pk2-pack to bf16 + v_permlane32_swap_b32
//   rebuilds PV A-fragments in-register (fragment = {s1.a, s2.a, s1.b, s2.b}).
// - V B-fragments read straight from Vs[hs][kk] (8 contiguous k per lane).
// - R5's proven counted-vmcnt staging skeleton (stage/vmcnt(4)/s_barrier).
__global__ __launch_bounds__(256, 2) void k_attn(
    const u16* __restrict__ Qg, const u16* __restrict__ Kg,
    const u16* __restrict__ Vt, u16* __restrict__ Og) {  // Og: [4096][1024] bf16
  __shared__ alignas(16) u16 Ks[2][64 * 64];
  __shared__ alignas(16) u16 Vs[2][64 * 64];   // [hs][kk]
  __shared__ float Ls[4][32];                  // per-wave 1/l broadcast
  const int tid = threadIdx.x, lane = tid & 63, w = tid >> 6;  // w in 0..3
  const int q32 = lane & 31, hi = lane >> 5;
  const int id = blockIdx.x;                   // 256 blocks
  const int xr = id & 7, j = id >> 3;          // j in 0..31
  const int bh = (j >> 3) * 8 + xr;            // 4 bh per XCD slot
  const int tA = j & 7, tB = 15 - tA;          // 128-row q-tiles, pair sum 34
  const int nkbA = 2 * tA + 2;                 // iters for tile A (NT=34)
  const u16* Qh = Qg + (size_t)bh * 2048 * 64;
  const u16* Kh = Kg + (size_t)bh * 2048 * 64;
  const u16* Vh = Vt + (size_t)bh * 64 * 2048;
  const int bb = bh >> 4, h = bh & 15;

  // staging source swizzle: lane (r8,j8) fetches global chunk j8^r8 of its row
  const int r8 = lane >> 3, j8 = lane & 7;
  const int sw_c = (j8 ^ r8) * 8;

  auto stage = [&](int i, int b) {
    const int kk0 = (i < nkbA ? i : i - nkbA) * 64;
    for (int t = 0; t < 2; ++t) {
      int row = w * 16 + t * 8;
      gld16(Kh + (size_t)(kk0 + row + r8) * 64 + sw_c, &Ks[b][row * 64]);
      gld16(Vh + (size_t)(row + r8) * 2048 + kk0 + sw_c, &Vs[b][row * 64]);
    }
  };

  // Q fragments for tile A: B-operand layout: col=q32, k = hi*8+j (K=16/mfma)
  bf16x8 aq[4];
  {
    const u16* qp = Qh + (size_t)(tA * 128 + w * 32 + q32) * 64 + hi * 8;
#pragma unroll
    for (int ds = 0; ds < 4; ++ds) aq[ds] = *(const bf16x8*)(qp + ds * 16);
  }
  asm volatile("" ::: "memory");  // aq loads oldest in vmcnt order
  stage(0, 0);
  stage(1, 1);

  f32x16 O0 = {}, O1 = {};        // O^T fragments: d = dh*32 + q32
  float lsum = 0.f;
  int qb = tA * 128;
  int kcap = 2 * tA + (w >> 1);   // last active kv-block for this wave

  for (int it = 0; it < 34; ++it) {
    const int buf = it & 1;
    if (it == 33) asm volatile("s_waitcnt vmcnt(0)" ::: "memory");
    else          asm volatile("s_waitcnt vmcnt(4)" ::: "memory");
    asm volatile("s_barrier" ::: "memory");   // staged buf visible to all

    const bool isA = it < nkbA;
    const int kb = isA ? it : it - nkbA;

    if (kb <= kcap) {
      const int k0 = kb * 64;
      // ---- S^T = K.Q^T : two 32-k tiles, 4 d-slices each
      f32x16 st0 = {}, st1 = {};
#pragma unroll
      for (int ds = 0; ds < 4; ++ds) {
        const int c = ((ds * 2 + hi) ^ (q32 & 7)) * 8;
        bf16x8 ak0 = *(const bf16x8*)&Ks[buf][q32 * 64 + c];
        bf16x8 ak1 = *(const bf16x8*)&Ks[buf][(32 + q32) * 64 + c];
        st0 = __builtin_amdgcn_mfma_f32_32x32x16_bf16(ak0, aq[ds], st0, 0, 0, 0);
        st1 = __builtin_amdgcn_mfma_f32_32x32x16_bf16(ak1, aq[ds], st1, 0, 0, 0);
      }

      // ---- p = exp2(s) (scale folded into Q); mask only on diagonal block
      float p0[16], p1[16];
      if (kb == kcap) {
        const int q = qb + w * 32 + q32;
#pragma unroll
        for (int r = 0; r < 16; ++r) {
          int kk = k0 + (r & 3) + 8 * (r >> 2) + 4 * hi;
          float e0 = __builtin_amdgcn_exp2f(st0[r]);
          float e1 = __builtin_amdgcn_exp2f(st1[r]);
          p0[r] = (kk <= q) ? e0 : 0.f;
          p1[r] = (kk + 32 <= q) ? e1 : 0.f;
          lsum += p0[r] + p1[r];
        }
      } else {
#pragma unroll
        for (int r = 0; r < 16; ++r) {
          p0[r] = __builtin_amdgcn_exp2f(st0[r]);
          p1[r] = __builtin_amdgcn_exp2f(st1[r]);
          lsum += p0[r] + p1[r];
        }
      }

      // ---- in-register P->bf16 PV A-fragments via permlane32_swap
      // slice s (=kt*2+kl) covers k = s*16 + hi*8 + j
      u32 paw[4][4];
#pragma unroll
      for (int kt = 0; kt < 2; ++kt) {
        const float* P = kt ? p1 : p0;
#pragma unroll
        for (int kl = 0; kl < 2; ++kl) {
          const int b0i = kl * 8;
          u32 a0 = pk2(P[b0i + 0], P[b0i + 1]);
          u32 b0 = pk2(P[b0i + 4], P[b0i + 5]);
          u32 a1 = pk2(P[b0i + 2], P[b0i + 3]);
          u32 b1 = pk2(P[b0i + 6], P[b0i + 7]);
          asm volatile("v_permlane32_swap_b32 %0, %1" : "+v"(a0), "+v"(b0));
          asm volatile("v_permlane32_swap_b32 %0, %1" : "+v"(a1), "+v"(b1));
          const int s = kt * 2 + kl;
          paw[s][0] = a0; paw[s][1] = a1; paw[s][2] = b0; paw[s][3] = b1;
        }
      }

      // ---- O^T += P.V : 4 k-slices x 2 d-halves
#pragma unroll
      for (int s = 0; s < 4; ++s) {
        u32x4 pw = { paw[s][0], paw[s][1], paw[s][2], paw[s][3] };
        bf16x8 pa = __builtin_bit_cast(bf16x8, pw);
        const int c = ((s * 2 + hi) ^ (q32 & 7)) * 8;
        bf16x8 bv0 = *(const bf16x8*)&Vs[buf][q32 * 64 + c];
        bf16x8 bv1 = *(const bf16x8*)&Vs[buf][(32 + q32) * 64 + c];
        O0 = __builtin_amdgcn_mfma_f32_32x32x16_bf16(pa, bv0, O0, 0, 0, 0);
        O1 = __builtin_amdgcn_mfma_f32_32x32x16_bf16(pa, bv1, O1, 0, 0, 0);
      }
    }

    // all waves done reading buf -> safe to re-stage with block it+2
    asm volatile("s_barrier" ::: "memory");
    if (it + 2 < 34) stage(it + 2, buf);

    // ---- tile-A epilogue (block-uniform), overlaps next staging
    if (it == nkbA - 1) {
      float lt = lsum + __shfl_xor(lsum, 32, 64);
      float invl = 1.0f / lt;
      if (lane < 32) Ls[w][q32] = invl;
      u16* dst = Og + ((size_t)bb * 2048 + tA * 128 + w * 32) * 1024 + h * 64 + q32;
#pragma unroll
      for (int r = 0; r < 16; ++r) {
        int qp = (r & 3) + 8 * (r >> 2) + 4 * hi;
        float iv = Ls[w][qp];
        dst[(size_t)qp * 1024]      = f2bf(O0[r] * iv);
        dst[(size_t)qp * 1024 + 32] = f2bf(O1[r] * iv);
      }
      // reset for tile B
      lsum = 0.f;
      O0 = {}; O1 = {};
      const u16* qp = Qh + (size_t)(tB * 128 + w * 32 + q32) * 64 + hi * 8;
#pragma unroll
      for (int ds = 0; ds < 4; ++ds) aq[ds] = *(const bf16x8*)(qp + ds * 16);
      qb = tB * 128;
      kcap = 2 * tB + (w >> 1);
    }
  }

  // ---- tile-B epilogue
  {
    float lt = lsum + __shfl_xor(lsum, 32, 64);
    float invl = 1.0f / lt;
    if (lane < 32) Ls[w][q32] = invl;
    u16* dst = Og + ((size_t)bb * 2048 + tB * 128 + w * 32) * 1024 + h * 64 + q32;
#pragma unroll
    for (int r = 0; r < 16; ++r) {
      int qp = (r & 3) + 8 * (r >> 2) + 4 * hi;
      float iv = Ls[w][qp];
      dst[(size_t)qp * 1024]      = f2bf(O0[r] * iv);
      dst[(size_t)qp * 1024 + 32] = f2bf(O1[r] * iv);
    }
  }
}

// --------------------- output projection GEMM ---------------------
// BM=64, BN=128, BK=64, swizzled staging. grid (8, 64) = 512 blocks (2/CU).
__global__ __launch_bounds__(256, 4) void k_proj(
    const u16* __restrict__ Ag,      // [4096][1024] bf16
    const u16* __restrict__ Wt,      // [1024][1024] bf16 (W_proj^T)
    const float* __restrict__ bias,  // [1024]
    float* __restrict__ out) {       // [4096][1024] f32
  __shared__ alignas(16) u16 As[64 * 64];
  __shared__ alignas(16) u16 Bs[128 * 64];
  const int tid = threadIdx.x;
  const int lane = tid & 63, w = tid >> 6;
  const int quad = lane >> 4, l15 = lane & 15;
  const int m0 = blockIdx.y * 64, n0 = blockIdx.x * 128;
  const int wm = (w & 1) * 32, wn = (w >> 1) * 64;
  const int srow = lane >> 3, sj = lane & 7;
  const int sw = (sj ^ srow) * 8;
  const f32x4 vzero = {0.f, 0.f, 0.f, 0.f};

  f32x4 acc[2][4];
  for (int i = 0; i < 2; ++i)
    for (int j = 0; j < 4; ++j) acc[i][j] = vzero;

  for (int kt = 0; kt < 1024; kt += 64) {
    __syncthreads();
    for (int i = 0; i < 2; ++i) {
      int row = w * 16 + i * 8;
      gld16(Ag + (size_t)(m0 + row + srow) * 1024 + kt + sw, &As[row * 64]);
    }
    for (int i = 0; i < 4; ++i) {
      int row = w * 32 + i * 8;
      gld16(Wt + (size_t)(n0 + row + srow) * 1024 + kt + sw, &Bs[row * 64]);
    }
    __syncthreads();
    for (int ks = 0; ks < 2; ++ks) {
      const int cc = ((ks * 4 + quad) ^ (l15 & 7)) * 8;
      bf16x8 a[2], b[4];
      for (int mt = 0; mt < 2; ++mt)
        a[mt] = *(const bf16x8*)&As[(wm + mt * 16 + l15) * 64 + cc];
      for (int nt = 0; nt < 4; ++nt)
        b[nt] = *(const bf16x8*)&Bs[(wn + nt * 16 + l15) * 64 + cc];
      for (int mt = 0; mt < 2; ++mt)
        for (int nt = 0; nt < 4; ++nt)
          acc[mt][nt] = __builtin_amdgcn_mfma_f32_16x16x32_bf16(
              a[mt], b[nt], acc[mt][nt], 0, 0, 0);
    }
  }

  for (int nt = 0; nt < 4; ++nt) {
    int n = n0 + wn + nt * 16 + l15;
    float bv = bias[n];
    for (int mt = 0; mt < 2; ++mt)
      for (int r = 0; r < 4; ++r) {
        int m = m0 + wm + mt * 16 + quad * 4 + r;
        out[(size_t)m * 1024 + n] = acc[mt][nt][r] + bv;
      }
  }
}

extern "C" void kernel_launch(void* const* d_in, const int* in_sizes, int n_in,
                              void* d_out, int out_size, void* d_ws, size_t ws_size,
                              hipStream_t stream) {
  (void)in_sizes; (void)n_in; (void)out_size; (void)ws_size;
  const float* x     = (const float*)d_in[0];
  const float* Wqkv  = (const float*)d_in[1];
  const float* bqkv  = (const float*)d_in[2];
  const float* Wproj = (const float*)d_in[3];
  const float* bproj = (const float*)d_in[4];
  float* out = (float*)d_out;

  char* ws = (char*)d_ws;
  size_t off = 0;
  u16* Xb    = (u16*)(ws + off); off += (size_t)4096 * 1024 * 2;   // x bf16
  u16* Wqkvt = (u16*)(ws + off); off += (size_t)3072 * 1024 * 2;   // W_qkv^T bf16
  u16* Wpt   = (u16*)(ws + off); off += (size_t)1024 * 1024 * 2;   // W_proj^T bf16
  u16* Qg    = (u16*)(ws + off); off += (size_t)2 * 16 * 2048 * 64 * 2;
  u16* Kg    = (u16*)(ws + off); off += (size_t)2 * 16 * 2048 * 64 * 2;
  u16* Vt    = (u16*)(ws + off); off += (size_t)2 * 16 * 64 * 2048 * 2;
  u16* Att   = (u16*)(ws + off); off += (size_t)4096 * 1024 * 2;
  float2* rope = (float2*)(ws + off); off += (size_t)2048 * 32 * sizeof(float2);

  k_prep<<<8448, 256, 0, stream>>>(x, Xb, Wqkv, Wqkvt, Wproj, Wpt, rope);
  k_qkv<<<dim3(24, 32), 256, 0, stream>>>(Xb, Wqkvt, bqkv, rope, Qg, Kg, Vt);
  k_attn<<<256, 256, 0, stream>>>(Qg, Kg, Vt, Att);
  k_proj<<<dim3(8, 64), 256, 0, stream>>>(Att, Wpt, bproj, out);
}

// Round 7
// 170.265 us; speedup vs baseline: 1.0062x; 1.0062x over previous
//
#include <hip/hip_runtime.h>

// Problem constants: B=2, T=2048, C=1024, H=16, HS=64
typedef unsigned short u16;
typedef unsigned int u32;
typedef __bf16 bf16x8 __attribute__((ext_vector_type(8)));
typedef float f32x4 __attribute__((ext_vector_type(4)));
typedef float f32x16 __attribute__((ext_vector_type(16)));
typedef u32 u32x4 __attribute__((ext_vector_type(4)));
typedef u16 u16x4 __attribute__((ext_vector_type(4)));
typedef u16 u16x8 __attribute__((ext_vector_type(8)));

__device__ __forceinline__ u16 f2bf(float f) {
  u32 u = __builtin_bit_cast(u32, f);
  u += 0x7fffu + ((u >> 16) & 1u);   // round-to-nearest-even
  return (u16)(u >> 16);
}

// pack two f32 -> two bf16 (round-half-up) in one u32; a in low half.
__device__ __forceinline__ u32 pk2(float a, float b) {
  u32 ua = __builtin_bit_cast(u32, a) + 0x8000u;
  u32 ub = __builtin_bit_cast(u32, b) + 0x8000u;
  return __builtin_amdgcn_perm(ub, ua, 0x07060302);  // {ub.hi16, ua.hi16}
}

__device__ __forceinline__ void gld16(const void* g, void* l) {
  __builtin_amdgcn_global_load_lds(
      (const __attribute__((address_space(1))) void*)g,
      (__attribute__((address_space(3))) void*)l, 16, 0, 0);
}

// ---------------- merged prep kernel (one launch) ----------------
__global__ __launch_bounds__(256) void k_prep(
    const float* __restrict__ x, u16* __restrict__ xb,
    const float* __restrict__ Wqkv, u16* __restrict__ Wqkvt,
    const float* __restrict__ Wproj, u16* __restrict__ Wpt,
    float2* __restrict__ rope) {
  __shared__ float tile[32][33];
  const int tid = threadIdx.x;
  int bx = blockIdx.x;
  if (bx < 4096) {
    int i = (bx * 256 + tid) * 4;
    float4 v = *(const float4*)(x + i);
    u16x4 o = { f2bf(v.x), f2bf(v.y), f2bf(v.z), f2bf(v.w) };
    *(u16x4*)(xb + i) = o;
    return;
  }
  bx -= 4096;
  const float* src; u16* dst; int R, Cc, bxx, byy;
  if (bx < 3072) {
    src = Wqkv; dst = Wqkvt; R = 1024; Cc = 3072; bxx = bx % 96; byy = bx / 96;
  } else if (bx < 4096) {
    int b = bx - 3072;
    src = Wproj; dst = Wpt; R = 1024; Cc = 1024; bxx = b % 32; byy = b / 32;
  } else {
    int i = (bx - 4096) * 256 + tid;  // 0..65535
    int t = i >> 5, d = i & 31;
    float theta = expf(-(float)d * 0.28782313662425575f);  // ln(10000)/32
    float ang = (float)t * theta;
    rope[i] = make_float2(cosf(ang), sinf(ang));
    return;
  }
  int xx = tid & 31, yy = tid >> 5;
  int c0 = bxx * 32, r0 = byy * 32;
  for (int i = 0; i < 4; ++i)
    tile[yy + 8 * i][xx] = src[(size_t)(r0 + yy + 8 * i) * Cc + c0 + xx];
  __syncthreads();
  for (int i = 0; i < 4; ++i)
    dst[(size_t)(c0 + yy + 8 * i) * R + r0 + xx] = f2bf(tile[xx][yy + 8 * i]);
}

// --------------- QKV GEMM + bias + RoPE + scatter ---------------
// Q is pre-scaled by 1/sqrt(HS)*log2(e) here so k_attn's softmax is a bare
// exp2 of the MFMA output.
__global__ __launch_bounds__(256, 4) void k_qkv(
    const u16* __restrict__ Xb,      // [4096][1024] bf16
    const u16* __restrict__ Wt,      // [3072][1024] bf16 (W_qkv^T)
    const float* __restrict__ bias,  // [3072]
    const float2* __restrict__ rope, // [2048][32]
    u16* __restrict__ Qg,            // [B,H,T,HS]  (scaled)
    u16* __restrict__ Kg,            // [B,H,T,HS]
    u16* __restrict__ Vt) {          // [B,H,HS,T]
  __shared__ alignas(16) u16 smem[18432];  // 36 KB: As|Bs in K-loop, Es after
  u16* As = smem;           // [128][64]
  u16* Bs = smem + 8192;    // [128][64]
  const int tid = threadIdx.x;
  const int lane = tid & 63, w = tid >> 6;
  const int quad = lane >> 4, l15 = lane & 15;
  const int m0 = blockIdx.y * 128, n0 = blockIdx.x * 128;
  const int wm = (w & 1) * 64, wn = (w >> 1) * 64;
  const int srow = lane >> 3, sj = lane & 7;
  const int sw = (sj ^ srow) * 8;   // swizzled source u16 offset
  const f32x4 vzero = {0.f, 0.f, 0.f, 0.f};

  f32x4 acc[4][4];  // [nt][mt] (swapped order)
  for (int i = 0; i < 4; ++i)
    for (int j = 0; j < 4; ++j) acc[i][j] = vzero;

  for (int kt = 0; kt < 1024; kt += 64) {
    __syncthreads();
    for (int i = 0; i < 4; ++i) {
      int row = w * 32 + i * 8;
      gld16(Xb + (size_t)(m0 + row + srow) * 1024 + kt + sw, &As[row * 64]);
      gld16(Wt + (size_t)(n0 + row + srow) * 1024 + kt + sw, &Bs[row * 64]);
    }
    __syncthreads();
    for (int ks = 0; ks < 2; ++ks) {
      const int cc = ((ks * 4 + quad) ^ (l15 & 7)) * 8;
      bf16x8 a[4], b[4];
      for (int mt = 0; mt < 4; ++mt)
        a[mt] = *(const bf16x8*)&As[(wm + mt * 16 + l15) * 64 + cc];
      for (int nt = 0; nt < 4; ++nt)
        b[nt] = *(const bf16x8*)&Bs[(wn + nt * 16 + l15) * 64 + cc];
      for (int nt = 0; nt < 4; ++nt)
        for (int mt = 0; mt < 4; ++mt)
          acc[nt][mt] = __builtin_amdgcn_mfma_f32_16x16x32_bf16(
              b[nt], a[mt], acc[nt][mt], 0, 0, 0);
    }
  }
  __syncthreads();  // all waves done reading As/Bs; safe to overwrite with Es

  // ---- stage into LDS (bias + RoPE applied), wave-uniform region per half
  const int half = w >> 1;
  const int nh = n0 + half * 64;             // 64-aligned -> single region
  const int region = (nh % 192) >> 6;        // 0=Q 1=K 2=V
  u16* Eh = smem + half * 9216;
  if (region < 2) {
    const float qsc = (region == 0) ? 0.18033688011112042f : 1.0f; // SCL into Q
    for (int nt = 0; nt < 4; ++nt) {
      float4 bv4 = *(const float4*)&bias[nh + nt * 16 + quad * 4];
      for (int mt = 0; mt < 4; ++mt) {
        int m_l = wm + mt * 16 + l15;
        int t = (m0 + m_l) & 2047;
        float4 cs = *(const float4*)&rope[t * 32 + nt * 8 + quad * 2];
        float v0 = acc[nt][mt][0] + bv4.x;
        float v1 = acc[nt][mt][1] + bv4.y;
        float v2 = acc[nt][mt][2] + bv4.z;
        float v3 = acc[nt][mt][3] + bv4.w;
        float r0 = fmaf(-v1, cs.y, v0 * cs.x) * qsc;
        float r1 = fmaf( v0, cs.y, v1 * cs.x) * qsc;
        float r2 = fmaf(-v3, cs.w, v2 * cs.z) * qsc;
        float r3 = fmaf( v2, cs.w, v3 * cs.z) * qsc;
        uint2 pv; pv.x = pk2(r0, r1); pv.y = pk2(r2, r3);
        *(uint2*)&Eh[m_l * 72 + nt * 16 + quad * 4] = pv;
      }
    }
  } else {
    // V: transposed [c][m] stride 136; c = nt*16+quad*4+r varies with r
    for (int nt = 0; nt < 4; ++nt) {
      float4 bv4 = *(const float4*)&bias[nh + nt * 16 + quad * 4];
      for (int mt = 0; mt < 4; ++mt) {
        int m_l = wm + mt * 16 + l15;
        int cb = nt * 16 + quad * 4;
        Eh[(cb + 0) * 136 + m_l] = f2bf(acc[nt][mt][0] + bv4.x);
        Eh[(cb + 1) * 136 + m_l] = f2bf(acc[nt][mt][1] + bv4.y);
        Eh[(cb + 2) * 136 + m_l] = f2bf(acc[nt][mt][2] + bv4.z);
        Eh[(cb + 3) * 136 + m_l] = f2bf(acc[nt][mt][3] + bv4.w);
      }
    }
  }
  __syncthreads();

  // ---- coalesced write-out: 16 B per lane
  const int bb = m0 >> 11, t0 = m0 & 2047;
  for (int hf = 0; hf < 2; ++hf) {
    const int nhf = n0 + hf * 64;
    const int hh = nhf / 192;
    const int reg = (nhf % 192) >> 6;
    const u16* Ef = smem + hf * 9216;
    if (reg < 2) {
      u16* dst = (reg == 0 ? Qg : Kg) +
                 ((size_t)(bb * 16 + hh) * 2048 + t0) * 64;
      int chunk = tid & 7, row0 = tid >> 3;
      for (int p = 0; p < 4; ++p) {
        int row = row0 + p * 32;
        u16x8 val = *(const u16x8*)&Ef[row * 72 + chunk * 8];
        *(u16x8*)(dst + (size_t)row * 64 + chunk * 8) = val;
      }
    } else {
      u16* dstv = Vt + (size_t)(bb * 16 + hh) * 64 * 2048 + t0;
      int mch = tid & 15, c0r = tid >> 4;
      for (int p = 0; p < 4; ++p) {
        int c = c0r + p * 16;
        u16x8 val = *(const u16x8*)&Ef[c * 136 + mch * 8];
        *(u16x8*)(dstv + (size_t)c * 2048 + mch * 8) = val;
      }
    }
  }
}

// ------------------- flash attention (causal) -------------------
// R7 = R6 inner loop (32x32 swapped QK^T, in-register softmax via
// pk2+permlane32_swap, counted-vmcnt dbuf staging) with restored TLP:
// 512 blocks, each owning ONE 128-row q-tile (512 tiles = 32 bh x 16).
// -> 2 blocks/CU co-resident = 2 independent chains per SIMD (R6 had 1).
// Triangular work (2t+2 iters) handled by LPT dispatch order: ids 0..255
// carry t=15..8 (big first), ids 256..511 carry t=7..0; the HW scheduler
// backfills finished CUs. XCD-affine bh decode kept (bh ≡ id mod 8).
__global__ __launch_bounds__(256, 2) void k_attn(
    const u16* __restrict__ Qg, const u16* __restrict__ Kg,
    const u16* __restrict__ Vt, u16* __restrict__ Og) {  // Og: [4096][1024] bf16
  __shared__ alignas(16) u16 Ks[2][64 * 64];
  __shared__ alignas(16) u16 Vs[2][64 * 64];   // [hs][kk]
  __shared__ float Ls[4][32];                  // per-wave 1/l broadcast
  const int tid = threadIdx.x, lane = tid & 63, w = tid >> 6;  // w in 0..3
  const int q32 = lane & 31, hi = lane >> 5;
  const int id = blockIdx.x;                   // 512 blocks
  const int xr = id & 7, m = id >> 3;          // m in 0..63
  int t, grp;
  if (m < 32) { t = 15 - (m & 7); grp = m >> 3; }        // big tiles first
  else        { int mm = m - 32; t = 7 - (mm & 7); grp = mm >> 3; }
  const int bh = grp * 8 + xr;                 // bh ≡ xr (mod 8): XCD affinity
  const int nkb = 2 * t + 2;                   // KV-block iterations
  const u16* Qh = Qg + (size_t)bh * 2048 * 64;
  const u16* Kh = Kg + (size_t)bh * 2048 * 64;
  const u16* Vh = Vt + (size_t)bh * 64 * 2048;
  const int bb = bh >> 4, h = bh & 15;

  // staging source swizzle: lane (r8,j8) fetches global chunk j8^r8 of its row
  const int r8 = lane >> 3, j8 = lane & 7;
  const int sw_c = (j8 ^ r8) * 8;

  auto stage = [&](int i, int b) {
    const int kk0 = i * 64;
    for (int tt = 0; tt < 2; ++tt) {
      int row = w * 16 + tt * 8;
      gld16(Kh + (size_t)(kk0 + row + r8) * 64 + sw_c, &Ks[b][row * 64]);
      gld16(Vh + (size_t)(row + r8) * 2048 + kk0 + sw_c, &Vs[b][row * 64]);
    }
  };

  // Q fragments: B-operand layout: col=q32, k = hi*8+j (K=16/mfma)
  bf16x8 aq[4];
  {
    const u16* qp = Qh + (size_t)(t * 128 + w * 32 + q32) * 64 + hi * 8;
#pragma unroll
    for (int ds = 0; ds < 4; ++ds) aq[ds] = *(const bf16x8*)(qp + ds * 16);
  }
  asm volatile("" ::: "memory");  // aq loads oldest in vmcnt order
  stage(0, 0);
  stage(1, 1);

  f32x16 O0 = {}, O1 = {};        // O^T fragments: d = dh*32 + q32
  float lsum = 0.f;
  const int kcap = 2 * t + (w >> 1);   // last active kv-block for this wave

  for (int it = 0; it < nkb; ++it) {
    const int buf = it & 1;
    if (it == nkb - 1) asm volatile("s_waitcnt vmcnt(0)" ::: "memory");
    else               asm volatile("s_waitcnt vmcnt(4)" ::: "memory");
    asm volatile("s_barrier" ::: "memory");   // staged buf visible to all

    const int kb = it;
    if (kb <= kcap) {
      const int k0 = kb * 64;
      // ---- S^T = K.Q^T : two 32-k tiles, 4 d-slices each
      f32x16 st0 = {}, st1 = {};
#pragma unroll
      for (int ds = 0; ds < 4; ++ds) {
        const int c = ((ds * 2 + hi) ^ (q32 & 7)) * 8;
        bf16x8 ak0 = *(const bf16x8*)&Ks[buf][q32 * 64 + c];
        bf16x8 ak1 = *(const bf16x8*)&Ks[buf][(32 + q32) * 64 + c];
        st0 = __builtin_amdgcn_mfma_f32_32x32x16_bf16(ak0, aq[ds], st0, 0, 0, 0);
        st1 = __builtin_amdgcn_mfma_f32_32x32x16_bf16(ak1, aq[ds], st1, 0, 0, 0);
      }

      // ---- p = exp2(s) (scale folded into Q); mask only on diagonal block
      float p0[16], p1[16];
      if (kb == kcap) {
        const int q = t * 128 + w * 32 + q32;
#pragma unroll
        for (int r = 0; r < 16; ++r) {
          int kk = k0 + (r & 3) + 8 * (r >> 2) + 4 * hi;
          float e0 = __builtin_amdgcn_exp2f(st0[r]);
          float e1 = __builtin_amdgcn_exp2f(st1[r]);
          p0[r] = (kk <= q) ? e0 : 0.f;
          p1[r] = (kk + 32 <= q) ? e1 : 0.f;
          lsum += p0[r] + p1[r];
        }
      } else {
#pragma unroll
        for (int r = 0; r < 16; ++r) {
          p0[r] = __builtin_amdgcn_exp2f(st0[r]);
          p1[r] = __builtin_amdgcn_exp2f(st1[r]);
          lsum += p0[r] + p1[r];
        }
      }

      // ---- in-register P->bf16 PV A-fragments via permlane32_swap
      // slice s (=kt*2+kl) covers k = s*16 + hi*8 + j
      u32 paw[4][4];
#pragma unroll
      for (int kt = 0; kt < 2; ++kt) {
        const float* P = kt ? p1 : p0;
#pragma unroll
        for (int kl = 0; kl < 2; ++kl) {
          const int b0i = kl * 8;
          u32 a0 = pk2(P[b0i + 0], P[b0i + 1]);
          u32 b0 = pk2(P[b0i + 4], P[b0i + 5]);
          u32 a1 = pk2(P[b0i + 2], P[b0i + 3]);
          u32 b1 = pk2(P[b0i + 6], P[b0i + 7]);
          asm volatile("v_permlane32_swap_b32 %0, %1" : "+v"(a0), "+v"(b0));
          asm volatile("v_permlane32_swap_b32 %0, %1" : "+v"(a1), "+v"(b1));
          const int s = kt * 2 + kl;
          paw[s][0] = a0; paw[s][1] = a1; paw[s][2] = b0; paw[s][3] = b1;
        }
      }

      // ---- O^T += P.V : 4 k-slices x 2 d-halves
#pragma unroll
      for (int s = 0; s < 4; ++s) {
        u32x4 pw = { paw[s][0], paw[s][1], paw[s][2], paw[s][3] };
        bf16x8 pa = __builtin_bit_cast(bf16x8, pw);
        const int c = ((s * 2 + hi) ^ (q32 & 7)) * 8;
        bf16x8 bv0 = *(const bf16x8*)&Vs[buf][q32 * 64 + c];
        bf16x8 bv1 = *(const bf16x8*)&Vs[buf][(32 + q32) * 64 + c];
        O0 = __builtin_amdgcn_mfma_f32_32x32x16_bf16(pa, bv0, O0, 0, 0, 0);
        O1 = __builtin_amdgcn_mfma_f32_32x32x16_bf16(pa, bv1, O1, 0, 0, 0);
      }
    }

    // all waves done reading buf -> safe to re-stage with block it+2
    asm volatile("s_barrier" ::: "memory");
    if (it + 2 < nkb) stage(it + 2, buf);
  }

  // ---- epilogue
  {
    float lt = lsum + __shfl_xor(lsum, 32, 64);
    float invl = 1.0f / lt;
    if (lane < 32) Ls[w][q32] = invl;
    u16* dst = Og + ((size_t)bb * 2048 + t * 128 + w * 32) * 1024 + h * 64 + q32;
#pragma unroll
    for (int r = 0; r < 16; ++r) {
      int qp = (r & 3) + 8 * (r >> 2) + 4 * hi;
      float iv = Ls[w][qp];
      dst[(size_t)qp * 1024]      = f2bf(O0[r] * iv);
      dst[(size_t)qp * 1024 + 32] = f2bf(O1[r] * iv);
    }
  }
}

// --------------------- output projection GEMM ---------------------
// BM=64, BN=128, BK=64, swizzled staging. grid (8, 64) = 512 blocks (2/CU).
__global__ __launch_bounds__(256, 4) void k_proj(
    const u16* __restrict__ Ag,      // [4096][1024] bf16
    const u16* __restrict__ Wt,      // [1024][1024] bf16 (W_proj^T)
    const float* __restrict__ bias,  // [1024]
    float* __restrict__ out) {       // [4096][1024] f32
  __shared__ alignas(16) u16 As[64 * 64];
  __shared__ alignas(16) u16 Bs[128 * 64];
  const int tid = threadIdx.x;
  const int lane = tid & 63, w = tid >> 6;
  const int quad = lane >> 4, l15 = lane & 15;
  const int m0 = blockIdx.y * 64, n0 = blockIdx.x * 128;
  const int wm = (w & 1) * 32, wn = (w >> 1) * 64;
  const int srow = lane >> 3, sj = lane & 7;
  const int sw = (sj ^ srow) * 8;
  const f32x4 vzero = {0.f, 0.f, 0.f, 0.f};

  f32x4 acc[2][4];
  for (int i = 0; i < 2; ++i)
    for (int j = 0; j < 4; ++j) acc[i][j] = vzero;

  for (int kt = 0; kt < 1024; kt += 64) {
    __syncthreads();
    for (int i = 0; i < 2; ++i) {
      int row = w * 16 + i * 8;
      gld16(Ag + (size_t)(m0 + row + srow) * 1024 + kt + sw, &As[row * 64]);
    }
    for (int i = 0; i < 4; ++i) {
      int row = w * 32 + i * 8;
      gld16(Wt + (size_t)(n0 + row + srow) * 1024 + kt + sw, &Bs[row * 64]);
    }
    __syncthreads();
    for (int ks = 0; ks < 2; ++ks) {
      const int cc = ((ks * 4 + quad) ^ (l15 & 7)) * 8;
      bf16x8 a[2], b[4];
      for (int mt = 0; mt < 2; ++mt)
        a[mt] = *(const bf16x8*)&As[(wm + mt * 16 + l15) * 64 + cc];
      for (int nt = 0; nt < 4; ++nt)
        b[nt] = *(const bf16x8*)&Bs[(wn + nt * 16 + l15) * 64 + cc];
      for (int mt = 0; mt < 2; ++mt)
        for (int nt = 0; nt < 4; ++nt)
          acc[mt][nt] = __builtin_amdgcn_mfma_f32_16x16x32_bf16(
              a[mt], b[nt], acc[mt][nt], 0, 0, 0);
    }
  }

  for (int nt = 0; nt < 4; ++nt) {
    int n = n0 + wn + nt * 16 + l15;
    float bv = bias[n];
    for (int mt = 0; mt < 2; ++mt)
      for (int r = 0; r < 4; ++r) {
        int m = m0 + wm + mt * 16 + quad * 4 + r;
        out[(size_t)m * 1024 + n] = acc[mt][nt][r] + bv;
      }
  }
}

extern "C" void kernel_launch(void* const* d_in, const int* in_sizes, int n_in,
                              void* d_out, int out_size, void* d_ws, size_t ws_size,
                              hipStream_t stream) {
  (void)in_sizes; (void)n_in; (void)out_size; (void)ws_size;
  const float* x     = (const float*)d_in[0];
  const float* Wqkv  = (const float*)d_in[1];
  const float* bqkv  = (const float*)d_in[2];
  const float* Wproj = (const float*)d_in[3];
  const float* bproj = (const float*)d_in[4];
  float* out = (float*)d_out;

  char* ws = (char*)d_ws;
  size_t off = 0;
  u16* Xb    = (u16*)(ws + off); off += (size_t)4096 * 1024 * 2;   // x bf16
  u16* Wqkvt = (u16*)(ws + off); off += (size_t)3072 * 1024 * 2;   // W_qkv^T bf16
  u16* Wpt   = (u16*)(ws + off); off += (size_t)1024 * 1024 * 2;   // W_proj^T bf16
  u16* Qg    = (u16*)(ws + off); off += (size_t)2 * 16 * 2048 * 64 * 2;
  u16* Kg    = (u16*)(ws + off); off += (size_t)2 * 16 * 2048 * 64 * 2;
  u16* Vt    = (u16*)(ws + off); off += (size_t)2 * 16 * 64 * 2048 * 2;
  u16* Att   = (u16*)(ws + off); off += (size_t)4096 * 1024 * 2;
  float2* rope = (float2*)(ws + off); off += (size_t)2048 * 32 * sizeof(float2);

  k_prep<<<8448, 256, 0, stream>>>(x, Xb, Wqkv, Wqkvt, Wproj, Wpt, rope);
  k_qkv<<<dim3(24, 32), 256, 0, stream>>>(Xb, Wqkvt, bqkv, rope, Qg, Kg, Vt);
  k_attn<<<512, 256, 0, stream>>>(Qg, Kg, Vt, Att);
  k_proj<<<dim3(8, 64), 256, 0, stream>>>(Att, Wpt, bproj, out);
}

// Round 8
// 169.266 us; speedup vs baseline: 1.0122x; 1.0059x over previous
//
#include <hip/hip_runtime.h>

// Problem constants: B=2, T=2048, C=1024, H=16, HS=64
typedef unsigned short u16;
typedef unsigned int u32;
typedef __bf16 bf16x8 __attribute__((ext_vector_type(8)));
typedef float f32x4 __attribute__((ext_vector_type(4)));
typedef float f32x16 __attribute__((ext_vector_type(16)));
typedef u32 u32x4 __attribute__((ext_vector_type(4)));
typedef u16 u16x4 __attribute__((ext_vector_type(4)));
typedef u16 u16x8 __attribute__((ext_vector_type(8)));

__device__ __forceinline__ u16 f2bf(float f) {
  u32 u = __builtin_bit_cast(u32, f);
  u += 0x7fffu + ((u >> 16) & 1u);   // round-to-nearest-even
  return (u16)(u >> 16);
}

// pack two f32 -> two bf16 (round-half-up) in one u32; a in low half.
__device__ __forceinline__ u32 pk2(float a, float b) {
  u32 ua = __builtin_bit_cast(u32, a) + 0x8000u;
  u32 ub = __builtin_bit_cast(u32, b) + 0x8000u;
  return __builtin_amdgcn_perm(ub, ua, 0x07060302);  // {ub.hi16, ua.hi16}
}

__device__ __forceinline__ void gld16(const void* g, void* l) {
  __builtin_amdgcn_global_load_lds(
      (const __attribute__((address_space(1))) void*)g,
      (__attribute__((address_space(3))) void*)l, 16, 0, 0);
}

// ---------------- merged prep kernel (one launch) ----------------
__global__ __launch_bounds__(256) void k_prep(
    const float* __restrict__ x, u16* __restrict__ xb,
    const float* __restrict__ Wqkv, u16* __restrict__ Wqkvt,
    const float* __restrict__ Wproj, u16* __restrict__ Wpt,
    float2* __restrict__ rope) {
  __shared__ float tile[32][33];
  const int tid = threadIdx.x;
  int bx = blockIdx.x;
  if (bx < 4096) {
    int i = (bx * 256 + tid) * 4;
    float4 v = *(const float4*)(x + i);
    u16x4 o = { f2bf(v.x), f2bf(v.y), f2bf(v.z), f2bf(v.w) };
    *(u16x4*)(xb + i) = o;
    return;
  }
  bx -= 4096;
  const float* src; u16* dst; int R, Cc, bxx, byy;
  if (bx < 3072) {
    src = Wqkv; dst = Wqkvt; R = 1024; Cc = 3072; bxx = bx % 96; byy = bx / 96;
  } else if (bx < 4096) {
    int b = bx - 3072;
    src = Wproj; dst = Wpt; R = 1024; Cc = 1024; bxx = b % 32; byy = b / 32;
  } else {
    int i = (bx - 4096) * 256 + tid;  // 0..65535
    int t = i >> 5, d = i & 31;
    float theta = expf(-(float)d * 0.28782313662425575f);  // ln(10000)/32
    float ang = (float)t * theta;
    rope[i] = make_float2(cosf(ang), sinf(ang));
    return;
  }
  int xx = tid & 31, yy = tid >> 5;
  int c0 = bxx * 32, r0 = byy * 32;
  for (int i = 0; i < 4; ++i)
    tile[yy + 8 * i][xx] = src[(size_t)(r0 + yy + 8 * i) * Cc + c0 + xx];
  __syncthreads();
  for (int i = 0; i < 4; ++i)
    dst[(size_t)(c0 + yy + 8 * i) * R + r0 + xx] = f2bf(tile[xx][yy + 8 * i]);
}

// --------------- QKV GEMM + bias + RoPE + scatter ---------------
// Q is pre-scaled by 1/sqrt(HS)*log2(e) here so k_attn's softmax is a bare
// exp2 of the MFMA output.
__global__ __launch_bounds__(256, 4) void k_qkv(
    const u16* __restrict__ Xb,      // [4096][1024] bf16
    const u16* __restrict__ Wt,      // [3072][1024] bf16 (W_qkv^T)
    const float* __restrict__ bias,  // [3072]
    const float2* __restrict__ rope, // [2048][32]
    u16* __restrict__ Qg,            // [B,H,T,HS]  (scaled)
    u16* __restrict__ Kg,            // [B,H,T,HS]
    u16* __restrict__ Vt) {          // [B,H,HS,T]
  __shared__ alignas(16) u16 smem[18432];  // 36 KB: As|Bs in K-loop, Es after
  u16* As = smem;           // [128][64]
  u16* Bs = smem + 8192;    // [128][64]
  const int tid = threadIdx.x;
  const int lane = tid & 63, w = tid >> 6;
  const int quad = lane >> 4, l15 = lane & 15;
  const int m0 = blockIdx.y * 128, n0 = blockIdx.x * 128;
  const int wm = (w & 1) * 64, wn = (w >> 1) * 64;
  const int srow = lane >> 3, sj = lane & 7;
  const int sw = (sj ^ srow) * 8;   // swizzled source u16 offset
  const f32x4 vzero = {0.f, 0.f, 0.f, 0.f};

  f32x4 acc[4][4];  // [nt][mt] (swapped order)
  for (int i = 0; i < 4; ++i)
    for (int j = 0; j < 4; ++j) acc[i][j] = vzero;

  for (int kt = 0; kt < 1024; kt += 64) {
    __syncthreads();
    for (int i = 0; i < 4; ++i) {
      int row = w * 32 + i * 8;
      gld16(Xb + (size_t)(m0 + row + srow) * 1024 + kt + sw, &As[row * 64]);
      gld16(Wt + (size_t)(n0 + row + srow) * 1024 + kt + sw, &Bs[row * 64]);
    }
    __syncthreads();
    for (int ks = 0; ks < 2; ++ks) {
      const int cc = ((ks * 4 + quad) ^ (l15 & 7)) * 8;
      bf16x8 a[4], b[4];
      for (int mt = 0; mt < 4; ++mt)
        a[mt] = *(const bf16x8*)&As[(wm + mt * 16 + l15) * 64 + cc];
      for (int nt = 0; nt < 4; ++nt)
        b[nt] = *(const bf16x8*)&Bs[(wn + nt * 16 + l15) * 64 + cc];
      for (int nt = 0; nt < 4; ++nt)
        for (int mt = 0; mt < 4; ++mt)
          acc[nt][mt] = __builtin_amdgcn_mfma_f32_16x16x32_bf16(
              b[nt], a[mt], acc[nt][mt], 0, 0, 0);
    }
  }
  __syncthreads();  // all waves done reading As/Bs; safe to overwrite with Es

  // ---- stage into LDS (bias + RoPE applied), wave-uniform region per half
  const int half = w >> 1;
  const int nh = n0 + half * 64;             // 64-aligned -> single region
  const int region = (nh % 192) >> 6;        // 0=Q 1=K 2=V
  u16* Eh = smem + half * 9216;
  if (region < 2) {
    const float qsc = (region == 0) ? 0.18033688011112042f : 1.0f; // SCL into Q
    for (int nt = 0; nt < 4; ++nt) {
      float4 bv4 = *(const float4*)&bias[nh + nt * 16 + quad * 4];
      for (int mt = 0; mt < 4; ++mt) {
        int m_l = wm + mt * 16 + l15;
        int t = (m0 + m_l) & 2047;
        float4 cs = *(const float4*)&rope[t * 32 + nt * 8 + quad * 2];
        float v0 = acc[nt][mt][0] + bv4.x;
        float v1 = acc[nt][mt][1] + bv4.y;
        float v2 = acc[nt][mt][2] + bv4.z;
        float v3 = acc[nt][mt][3] + bv4.w;
        float r0 = fmaf(-v1, cs.y, v0 * cs.x) * qsc;
        float r1 = fmaf( v0, cs.y, v1 * cs.x) * qsc;
        float r2 = fmaf(-v3, cs.w, v2 * cs.z) * qsc;
        float r3 = fmaf( v2, cs.w, v3 * cs.z) * qsc;
        uint2 pv; pv.x = pk2(r0, r1); pv.y = pk2(r2, r3);
        *(uint2*)&Eh[m_l * 72 + nt * 16 + quad * 4] = pv;
      }
    }
  } else {
    // V: transposed [c][m] stride 136; c = nt*16+quad*4+r varies with r
    for (int nt = 0; nt < 4; ++nt) {
      float4 bv4 = *(const float4*)&bias[nh + nt * 16 + quad * 4];
      for (int mt = 0; mt < 4; ++mt) {
        int m_l = wm + mt * 16 + l15;
        int cb = nt * 16 + quad * 4;
        Eh[(cb + 0) * 136 + m_l] = f2bf(acc[nt][mt][0] + bv4.x);
        Eh[(cb + 1) * 136 + m_l] = f2bf(acc[nt][mt][1] + bv4.y);
        Eh[(cb + 2) * 136 + m_l] = f2bf(acc[nt][mt][2] + bv4.z);
        Eh[(cb + 3) * 136 + m_l] = f2bf(acc[nt][mt][3] + bv4.w);
      }
    }
  }
  __syncthreads();

  // ---- coalesced write-out: 16 B per lane
  const int bb = m0 >> 11, t0 = m0 & 2047;
  for (int hf = 0; hf < 2; ++hf) {
    const int nhf = n0 + hf * 64;
    const int hh = nhf / 192;
    const int reg = (nhf % 192) >> 6;
    const u16* Ef = smem + hf * 9216;
    if (reg < 2) {
      u16* dst = (reg == 0 ? Qg : Kg) +
                 ((size_t)(bb * 16 + hh) * 2048 + t0) * 64;
      int chunk = tid & 7, row0 = tid >> 3;
      for (int p = 0; p < 4; ++p) {
        int row = row0 + p * 32;
        u16x8 val = *(const u16x8*)&Ef[row * 72 + chunk * 8];
        *(u16x8*)(dst + (size_t)row * 64 + chunk * 8) = val;
      }
    } else {
      u16* dstv = Vt + (size_t)(bb * 16 + hh) * 64 * 2048 + t0;
      int mch = tid & 15, c0r = tid >> 4;
      for (int p = 0; p < 4; ++p) {
        int c = c0r + p * 16;
        u16x8 val = *(const u16x8*)&Ef[c * 136 + mch * 8];
        *(u16x8*)(dstv + (size_t)c * 2048 + mch * 8) = val;
      }
    }
  }
}

// ------------------- flash attention (causal) -------------------
// R8: MAX STRUCTURAL CO-RESIDENCY. 1024 blocks x 128 threads (2 waves),
// one 64-row q-tile per block (32 tiles x 32 bh). LDS 33 KB -> exactly
// 4 blocks/CU and ALL 1024 blocks resident from launch: 8 waves/CU =
// 2 independent 2-wave pipelines per SIMD for the whole kernel (every
// prior round effectively had ~1). Inner loop = R6/R7's verified 32x32
// swapped-QK^T + in-register softmax (pk2+permlane32_swap), counted-vmcnt
// dbuf staging (8 loads/wave per buffer -> vmcnt(8)).
// Per-CU work is constant BY CONSTRUCTION: within an XCD any round-robin
// CU assignment has period 32, so positions p and p+32 share a CU; with
// tau = (g&1) ? p' : 31-p' (g = bh-group = p>>5, p' = p&31) each CU's four
// blocks have tau-sum 62 (66 iters) regardless of the XCD's internal order.
__global__ __launch_bounds__(128, 2) void k_attn(
    const u16* __restrict__ Qg, const u16* __restrict__ Kg,
    const u16* __restrict__ Vt, u16* __restrict__ Og) {  // Og: [4096][1024] bf16
  __shared__ alignas(16) u16 Ks[2][64 * 64];
  __shared__ alignas(16) u16 Vs[2][64 * 64];   // [hs][kk]
  __shared__ float Ls[2][32];                  // per-wave 1/l broadcast
  const int tid = threadIdx.x, lane = tid & 63, w = tid >> 6;  // w in 0..1
  const int q32 = lane & 31, hi = lane >> 5;
  const int id = blockIdx.x;                   // 1024 blocks
  const int xr = id & 7, p = id >> 3;          // p in 0..127
  const int g = p >> 5, pp = p & 31;
  const int t = (g & 1) ? pp : 31 - pp;        // 64-row q-tile index 0..31
  const int bh = g * 8 + xr;                   // bh ≡ xr (mod 8): XCD affinity
  const int nkb = t + 1;                       // KV-block iterations
  const u16* Qh = Qg + (size_t)bh * 2048 * 64;
  const u16* Kh = Kg + (size_t)bh * 2048 * 64;
  const u16* Vh = Vt + (size_t)bh * 64 * 2048;
  const int bb = bh >> 4, h = bh & 15;
  const int q0 = t * 64 + w * 32;              // this wave's 32 q-rows

  // staging source swizzle: lane (r8,j8) fetches global chunk j8^r8 of its row
  const int r8 = lane >> 3, j8 = lane & 7;
  const int sw_c = (j8 ^ r8) * 8;

  // each wave stages 32 K-rows + 32 V-rows per buffer: 8 gld16 calls/wave
  auto stage = [&](int i, int b) {
    const int kk0 = i * 64;
    for (int tt = 0; tt < 4; ++tt) {
      int row = w * 32 + tt * 8;
      gld16(Kh + (size_t)(kk0 + row + r8) * 64 + sw_c, &Ks[b][row * 64]);
      gld16(Vh + (size_t)(row + r8) * 2048 + kk0 + sw_c, &Vs[b][row * 64]);
    }
  };

  // Q fragments: B-operand layout: col=q32, k = hi*8+j (K=16/mfma)
  bf16x8 aq[4];
  {
    const u16* qp = Qh + (size_t)(q0 + q32) * 64 + hi * 8;
#pragma unroll
    for (int ds = 0; ds < 4; ++ds) aq[ds] = *(const bf16x8*)(qp + ds * 16);
  }
  asm volatile("" ::: "memory");  // aq loads oldest in vmcnt order
  stage(0, 0);
  stage(1, 1);

  f32x16 O0 = {}, O1 = {};        // O^T fragments
  float lsum = 0.f;

  for (int it = 0; it < nkb; ++it) {
    const int buf = it & 1;
    // wait for THIS buffer's 8 loads (per-wave count); leave next 8 in flight
    if (it == nkb - 1) asm volatile("s_waitcnt vmcnt(0)" ::: "memory");
    else               asm volatile("s_waitcnt vmcnt(8)" ::: "memory");
    asm volatile("s_barrier" ::: "memory");   // staged buf visible to both waves

    const int k0 = it * 64;
    // ---- S^T = K.Q^T : two 32-k tiles, 4 d-slices each
    f32x16 st0 = {}, st1 = {};
#pragma unroll
    for (int ds = 0; ds < 4; ++ds) {
      const int c = ((ds * 2 + hi) ^ (q32 & 7)) * 8;
      bf16x8 ak0 = *(const bf16x8*)&Ks[buf][q32 * 64 + c];
      bf16x8 ak1 = *(const bf16x8*)&Ks[buf][(32 + q32) * 64 + c];
      st0 = __builtin_amdgcn_mfma_f32_32x32x16_bf16(ak0, aq[ds], st0, 0, 0, 0);
      st1 = __builtin_amdgcn_mfma_f32_32x32x16_bf16(ak1, aq[ds], st1, 0, 0, 0);
    }

    // ---- p = exp2(s) (scale folded into Q); mask only on diagonal block
    float p0[16], p1[16];
    if (it == nkb - 1) {   // diagonal block for this tile
      const int q = q0 + q32;
#pragma unroll
      for (int r = 0; r < 16; ++r) {
        int kk = k0 + (r & 3) + 8 * (r >> 2) + 4 * hi;
        float e0 = __builtin_amdgcn_exp2f(st0[r]);
        float e1 = __builtin_amdgcn_exp2f(st1[r]);
        p0[r] = (kk <= q) ? e0 : 0.f;
        p1[r] = (kk + 32 <= q) ? e1 : 0.f;
        lsum += p0[r] + p1[r];
      }
    } else {
#pragma unroll
      for (int r = 0; r < 16; ++r) {
        p0[r] = __builtin_amdgcn_exp2f(st0[r]);
        p1[r] = __builtin_amdgcn_exp2f(st1[r]);
        lsum += p0[r] + p1[r];
      }
    }

    // ---- in-register P->bf16 PV A-fragments via permlane32_swap
    u32 paw[4][4];
#pragma unroll
    for (int kt = 0; kt < 2; ++kt) {
      const float* P = kt ? p1 : p0;
#pragma unroll
      for (int kl = 0; kl < 2; ++kl) {
        const int b0i = kl * 8;
        u32 a0 = pk2(P[b0i + 0], P[b0i + 1]);
        u32 b0 = pk2(P[b0i + 4], P[b0i + 5]);
        u32 a1 = pk2(P[b0i + 2], P[b0i + 3]);
        u32 b1 = pk2(P[b0i + 6], P[b0i + 7]);
        asm volatile("v_permlane32_swap_b32 %0, %1" : "+v"(a0), "+v"(b0));
        asm volatile("v_permlane32_swap_b32 %0, %1" : "+v"(a1), "+v"(b1));
        const int s = kt * 2 + kl;
        paw[s][0] = a0; paw[s][1] = a1; paw[s][2] = b0; paw[s][3] = b1;
      }
    }

    // ---- O^T += P.V : 4 k-slices x 2 d-halves
#pragma unroll
    for (int s = 0; s < 4; ++s) {
      u32x4 pw = { paw[s][0], paw[s][1], paw[s][2], paw[s][3] };
      bf16x8 pa = __builtin_bit_cast(bf16x8, pw);
      const int c = ((s * 2 + hi) ^ (q32 & 7)) * 8;
      bf16x8 bv0 = *(const bf16x8*)&Vs[buf][q32 * 64 + c];
      bf16x8 bv1 = *(const bf16x8*)&Vs[buf][(32 + q32) * 64 + c];
      O0 = __builtin_amdgcn_mfma_f32_32x32x16_bf16(pa, bv0, O0, 0, 0, 0);
      O1 = __builtin_amdgcn_mfma_f32_32x32x16_bf16(pa, bv1, O1, 0, 0, 0);
    }

    // both waves done reading buf -> safe to re-stage with block it+2
    asm volatile("s_barrier" ::: "memory");
    if (it + 2 < nkb) stage(it + 2, buf);
  }

  // ---- epilogue
  {
    float lt = lsum + __shfl_xor(lsum, 32, 64);
    float invl = 1.0f / lt;
    if (lane < 32) Ls[w][q32] = invl;
    u16* dst = Og + ((size_t)bb * 2048 + q0) * 1024 + h * 64 + q32;
#pragma unroll
    for (int r = 0; r < 16; ++r) {
      int qp = (r & 3) + 8 * (r >> 2) + 4 * hi;
      float iv = Ls[w][qp];
      dst[(size_t)qp * 1024]      = f2bf(O0[r] * iv);
      dst[(size_t)qp * 1024 + 32] = f2bf(O1[r] * iv);
    }
  }
}

// --------------------- output projection GEMM ---------------------
// BM=64, BN=128, BK=64, swizzled staging. grid (8, 64) = 512 blocks (2/CU).
__global__ __launch_bounds__(256, 4) void k_proj(
    const u16* __restrict__ Ag,      // [4096][1024] bf16
    const u16* __restrict__ Wt,      // [1024][1024] bf16 (W_proj^T)
    const float* __restrict__ bias,  // [1024]
    float* __restrict__ out) {       // [4096][1024] f32
  __shared__ alignas(16) u16 As[64 * 64];
  __shared__ alignas(16) u16 Bs[128 * 64];
  const int tid = threadIdx.x;
  const int lane = tid & 63, w = tid >> 6;
  const int quad = lane >> 4, l15 = lane & 15;
  const int m0 = blockIdx.y * 64, n0 = blockIdx.x * 128;
  const int wm = (w & 1) * 32, wn = (w >> 1) * 64;
  const int srow = lane >> 3, sj = lane & 7;
  const int sw = (sj ^ srow) * 8;
  const f32x4 vzero = {0.f, 0.f, 0.f, 0.f};

  f32x4 acc[2][4];
  for (int i = 0; i < 2; ++i)
    for (int j = 0; j < 4; ++j) acc[i][j] = vzero;

  for (int kt = 0; kt < 1024; kt += 64) {
    __syncthreads();
    for (int i = 0; i < 2; ++i) {
      int row = w * 16 + i * 8;
      gld16(Ag + (size_t)(m0 + row + srow) * 1024 + kt + sw, &As[row * 64]);
    }
    for (int i = 0; i < 4; ++i) {
      int row = w * 32 + i * 8;
      gld16(Wt + (size_t)(n0 + row + srow) * 1024 + kt + sw, &Bs[row * 64]);
    }
    __syncthreads();
    for (int ks = 0; ks < 2; ++ks) {
      const int cc = ((ks * 4 + quad) ^ (l15 & 7)) * 8;
      bf16x8 a[2], b[4];
      for (int mt = 0; mt < 2; ++mt)
        a[mt] = *(const bf16x8*)&As[(wm + mt * 16 + l15) * 64 + cc];
      for (int nt = 0; nt < 4; ++nt)
        b[nt] = *(const bf16x8*)&Bs[(wn + nt * 16 + l15) * 64 + cc];
      for (int mt = 0; mt < 2; ++mt)
        for (int nt = 0; nt < 4; ++nt)
          acc[mt][nt] = __builtin_amdgcn_mfma_f32_16x16x32_bf16(
              a[mt], b[nt], acc[mt][nt], 0, 0, 0);
    }
  }

  for (int nt = 0; nt < 4; ++nt) {
    int n = n0 + wn + nt * 16 + l15;
    float bv = bias[n];
    for (int mt = 0; mt < 2; ++mt)
      for (int r = 0; r < 4; ++r) {
        int m = m0 + wm + mt * 16 + quad * 4 + r;
        out[(size_t)m * 1024 + n] = acc[mt][nt][r] + bv;
      }
  }
}

extern "C" void kernel_launch(void* const* d_in, const int* in_sizes, int n_in,
                              void* d_out, int out_size, void* d_ws, size_t ws_size,
                              hipStream_t stream) {
  (void)in_sizes; (void)n_in; (void)out_size; (void)ws_size;
  const float* x     = (const float*)d_in[0];
  const float* Wqkv  = (const float*)d_in[1];
  const float* bqkv  = (const float*)d_in[2];
  const float* Wproj = (const float*)d_in[3];
  const float* bproj = (const float*)d_in[4];
  float* out = (float*)d_out;

  char* ws = (char*)d_ws;
  size_t off = 0;
  u16* Xb    = (u16*)(ws + off); off += (size_t)4096 * 1024 * 2;   // x bf16
  u16* Wqkvt = (u16*)(ws + off); off += (size_t)3072 * 1024 * 2;   // W_qkv^T bf16
  u16* Wpt   = (u16*)(ws + off); off += (size_t)1024 * 1024 * 2;   // W_proj^T bf16
  u16* Qg    = (u16*)(ws + off); off += (size_t)2 * 16 * 2048 * 64 * 2;
  u16* Kg    = (u16*)(ws + off); off += (size_t)2 * 16 * 2048 * 64 * 2;
  u16* Vt    = (u16*)(ws + off); off += (size_t)2 * 16 * 64 * 2048 * 2;
  u16* Att   = (u16*)(ws + off); off += (size_t)4096 * 1024 * 2;
  float2* rope = (float2*)(ws + off); off += (size_t)2048 * 32 * sizeof(float2);

  k_prep<<<8448, 256, 0, stream>>>(x, Xb, Wqkv, Wqkvt, Wproj, Wpt, rope);
  k_qkv<<<dim3(24, 32), 256, 0, stream>>>(Xb, Wqkvt, bqkv, rope, Qg, Kg, Vt);
  k_attn<<<1024, 128, 0, stream>>>(Qg, Kg, Vt, Att);
  k_proj<<<dim3(8, 64), 256, 0, stream>>>(Att, Wpt, bproj, out);
}